// Round 16
// baseline (271.191 us; speedup 1.0000x reference)
//
#include <hip/hip_runtime.h>
#include <hip/hip_bf16.h>

#define C_  64
#define C3_ 192
#define T_  10
#define H_  128
#define W_  128
#define HW_ 16384        // H_*W_
#define THW_ 163840      // T_*HW_
#define NH_ 8
#define C2_ 24
#define TG_ 80           // t * SHUFFLE_G

typedef __hip_bfloat16 bf16;
typedef __attribute__((ext_vector_type(8))) short bf16x8;
typedef __attribute__((ext_vector_type(4))) float f32x4;

__device__ __forceinline__ float bf2f(bf16 v) { return __bfloat162float(v); }

__device__ __forceinline__ ushort f2bf_s(float f) {
  bf16 h = __float2bfloat16(f);
  union { bf16 b; ushort s; } u; u.b = h; return u.s;
}

__device__ __forceinline__ ushort4 pack4(f32x4 a) {
  ushort4 p;
  p.x = f2bf_s(a[0]); p.y = f2bf_s(a[1]); p.z = f2bf_s(a[2]); p.w = f2bf_s(a[3]);
  return p;
}

__device__ __forceinline__ uint pack2lo(uint x, uint y) { return (x & 0xffffu) | (y << 16); }
__device__ __forceinline__ uint pack2hi(uint x, uint y) { return (x >> 16) | (y & 0xffff0000u); }

// transpose 8x8 ushort block (rr[e][d] raw dwords) -> 8 k-contig uint4, write to lds
__device__ __forceinline__ void twrite(char* lds, int stride, int nkc,
                                       uint r[8][4], int kc, int cg) {
#pragma unroll
  for (int j = 0; j < 8; ++j) {
    const int d = j >> 1;
    uint4 o;
    if (j & 1) {
      o.x = pack2hi(r[0][d], r[1][d]); o.y = pack2hi(r[2][d], r[3][d]);
      o.z = pack2hi(r[4][d], r[5][d]); o.w = pack2hi(r[6][d], r[7][d]);
    } else {
      o.x = pack2lo(r[0][d], r[1][d]); o.y = pack2lo(r[2][d], r[3][d]);
      o.z = pack2lo(r[4][d], r[5][d]); o.w = pack2lo(r[6][d], r[7][d]);
    }
    const int col = cg * 8 + j;
    const int rr = (kc + col) % nkc;
    *reinterpret_cast<uint4*>(lds + col * stride + rr * 16) = o;
  }
}

// ================ KPREP: one-time f32 -> bf16 weight conversion ================
__global__ __launch_bounds__(256) void kprep(
    const float* __restrict__ W1, const float* __restrict__ W_lin,
    const float* __restrict__ W_out,
    bf16* __restrict__ W1bf, bf16* __restrict__ Wlinbf, bf16* __restrict__ Woutbf) {
  const int idx = blockIdx.x * 256 + threadIdx.x;
  if (idx < 12288) {
    W1bf[idx] = __float2bfloat16(W1[idx]);
  } else if (idx < 12288 + 7680) {
    const int i = idx - 12288;
    const int row = i / 96, col = i - row * 96;
    Wlinbf[i] = __float2bfloat16(col < 80 ? W_lin[row * 80 + col] : 0.f);
  } else if (idx < 12288 + 7680 + 4096) {
    const int i = idx - 12288 - 7680;
    Woutbf[i] = __float2bfloat16(W_out[i]);
  }
}

// ================ K1 (MFMA): y1 = W1 @ x, single 32KB buffer, 5 blocks/CU ================
__global__ __launch_bounds__(256, 5) void k1_mfma(
    const float* __restrict__ x, const bf16* __restrict__ W1bf,
    bf16* __restrict__ y1ws) {
  __shared__ __align__(16) float xs[64 * 128];   // 32,768 B
  const int tid = threadIdx.x;
  const int lane = tid & 63, wv = tid >> 6;
  const int lr = lane & 15, lg = lane >> 4;
  const int mh = blockIdx.y;
  const int b = blockIdx.z;
  const float* xb = x + (size_t)b * C_ * THW_;
  bf16* y1 = y1ws + (size_t)b * C3_ * THW_;
  const int n0 = blockIdx.x * 128;

  // DMA stage with source-XOR swizzle (LDS dest linear)
  {
    const int ro = lane >> 5, colo = (lane & 31) * 4;
#pragma unroll
    for (int i = 0; i < 8; ++i) {
      const int row = wv * 16 + i * 2;
      const int rr = row + ro;
      const int sw = (rr >> 3) & 1;
      const float* gsrc = xb + (size_t)rr * THW_ + n0 + (colo ^ (sw << 4));
      __builtin_amdgcn_global_load_lds(
          (const __attribute__((address_space(1))) void*)gsrc,
          (__attribute__((address_space(3))) void*)&xs[row * 128],
          16, 0, 0);
    }
  }

  bf16x8 wf[6][2];
#pragma unroll
  for (int mt = 0; mt < 6; ++mt)
#pragma unroll
    for (int c = 0; c < 2; ++c) {
      const int row = mh * 96 + mt * 16 + lr;
      wf[mt][c] = *reinterpret_cast<const bf16x8*>(W1bf + row * 64 + c * 32 + lg * 8);
    }
  __syncthreads();   // drains DMA

#pragma unroll
  for (int nt = 0; nt < 2; ++nt) {
    const int col = wv * 32 + nt * 16 + lr;
    const int col2 = col ^ ((lg & 1) << 4);           // un-swizzle at read
    bf16x8 xa[2];
#pragma unroll
    for (int c = 0; c < 2; ++c) {
      const float* base = &xs[(c * 32 + lg * 8) * 128 + col2];
      bf16x8 f;
#pragma unroll
      for (int e = 0; e < 8; ++e) f[e] = f2bf_s(base[e * 128]);
      xa[c] = f;
    }
    f32x4 acc[6];
#pragma unroll
    for (int mt = 0; mt < 6; ++mt) acc[mt] = (f32x4){0.f, 0.f, 0.f, 0.f};
#pragma unroll
    for (int c = 0; c < 2; ++c)
#pragma unroll
      for (int mt = 0; mt < 6; ++mt)
        acc[mt] = __builtin_amdgcn_mfma_f32_16x16x32_bf16(xa[c], wf[mt][c], acc[mt], 0, 0, 0);
    const int nb = n0 + wv * 32 + nt * 16 + lg * 4;
#pragma unroll
    for (int mt = 0; mt < 6; ++mt) {
      const int o = mh * 96 + mt * 16 + lr;
      *reinterpret_cast<ushort4*>(y1 + (size_t)o * THW_ + nb) = pack4(acc[mt]);
    }
  }
}

// ================ K2: depthwise 3x3, 32x128 tile, batch in grid.y ================
__global__ __launch_bounds__(256) void k2_dw(
    const bf16* __restrict__ y1ws, const float* __restrict__ Wdw,
    bf16* __restrict__ y2ws) {
  __shared__ float tile[34][132];
  const int tid = threadIdx.x;
  const int blk = blockIdx.x;
  const int b = blockIdx.y;
  const bf16* y1 = y1ws + (size_t)b * C3_ * THW_;
  bf16* y2 = y2ws + (size_t)b * C3_ * THW_;
  const int hs = (blk & 3) * 32;
  const int rest = blk >> 2;
  const int t = rest % T_;
  const int o = rest / T_;
  const bf16* src = y1 + ((size_t)o * T_ + t) * HW_;

  if (tid < 68) {
    const int r = tid >> 1, side = tid & 1;
    tile[r][side ? 129 : 0] = 0.f;
  }
  {
    const int rr = tid >> 5, c4 = (tid & 31) * 4;
#pragma unroll
    for (int p = 0; p < 5; ++p) {
      const int r = p * 8 + rr;
      if (r < 34) {
        const int hh = hs - 1 + r;
        float e0 = 0.f, e1 = 0.f, e2 = 0.f, e3 = 0.f;
        if (hh >= 0 && hh < H_) {
          uint2 raw = *reinterpret_cast<const uint2*>(src + hh * W_ + c4);
          e0 = __uint_as_float(raw.x << 16);
          e1 = __uint_as_float(raw.x & 0xffff0000u);
          e2 = __uint_as_float(raw.y << 16);
          e3 = __uint_as_float(raw.y & 0xffff0000u);
        }
        tile[r][1 + c4]     = e0;
        tile[r][1 + c4 + 1] = e1;
        tile[r][1 + c4 + 2] = e2;
        tile[r][1 + c4 + 3] = e3;
      }
    }
  }
  __syncthreads();

  float kk[9];
#pragma unroll
  for (int i = 0; i < 9; ++i) kk[i] = Wdw[o * 9 + i];

  bf16* dst = y2 + ((size_t)o * T_ + t) * HW_;
  const int w = tid & 127;
  const int r0 = (tid >> 7) * 16;

  float a[3][3];
#pragma unroll
  for (int ky = 0; ky < 3; ++ky)
#pragma unroll
    for (int kx = 0; kx < 3; ++kx) a[ky][kx] = tile[r0 + ky][w + kx];

#pragma unroll
  for (int q = 0; q < 16; ++q) {
    float acc = 0.f;
#pragma unroll
    for (int ky = 0; ky < 3; ++ky)
#pragma unroll
      for (int kx = 0; kx < 3; ++kx)
        acc = fmaf(kk[ky * 3 + kx], a[ky][kx], acc);
    dst[(hs + r0 + q) * W_ + w] = __float2bfloat16(acc);
    if (q < 15) {
#pragma unroll
      for (int kx = 0; kx < 3; ++kx) {
        a[0][kx] = a[1][kx];
        a[1][kx] = a[2][kx];
        a[2][kx] = tile[r0 + q + 3][w + kx];
      }
    }
  }
}

// ================ K3 (MFMA): z = W_lin @ shuffled(y2) + b, fused ssq, TPB pipeline,
//                  C-shuffle via LDS for coalesced 256B-per-row z stores ================
#define K3_NKC 13
#define K3_STRIDE 208
#define K3_TPB 4
#define CB_S 136   // cbuf row stride in bf16 elems
__global__ __launch_bounds__(256) void k3_mfma(
    const bf16* __restrict__ y2ws, const bf16* __restrict__ Wlinbf,
    const float* __restrict__ b_lin, bf16* __restrict__ zws,
    float* __restrict__ ssqws) {
  __shared__ __align__(16) char lds[256 * K3_STRIDE];   // 53,248 B
  __shared__ __align__(16) ushort cbuf[80 * CB_S];      // 21,760 B
  const int tid = threadIdx.x;
  const int tile0 = blockIdx.x * K3_TPB;
  const int c2 = blockIdx.y;
  const int b = blockIdx.z;
  const bf16* y2 = y2ws + (size_t)b * C3_ * THW_;
  bf16* z = zws + (size_t)b * C3_ * THW_;
  float* ssq = ssqws + b * 1280;

  const int lane = tid & 63, wv = tid >> 6;
  const int lr = lane & 15, lg = lane >> 4;

  const int kcA = tid >> 5, cgA = tid & 31;
  const bool hasB = (tid & 3) == 0;
  const int qB = tid >> 2;
  const int kcB = 8 + (qB >> 5), cgB = qB & 31;

  uint rrA[8][4], rrB[8][4];
  auto LOAD = [&](int s0, uint r[8][4], int kc, int cg) {
#pragma unroll
    for (int e = 0; e < 8; ++e) {
      const int k = kc * 8 + e;
      const int c1 = (k * 205) >> 11;        // k/10
      const int tt = k - c1 * 10;
      uint4 raw = *reinterpret_cast<const uint4*>(
          y2 + ((size_t)((c1 * C2_ + c2) * T_ + tt)) * HW_ + s0 + cg * 8);
      r[e][0] = raw.x; r[e][1] = raw.y; r[e][2] = raw.z; r[e][3] = raw.w;
    }
  };

  LOAD(tile0 * 256, rrA, kcA, cgA);
  if (hasB) LOAD(tile0 * 256, rrB, kcB, cgB);
  {
    const int col = tid;
    const uint4 zero4 = {0, 0, 0, 0};
    *reinterpret_cast<uint4*>(lds + col * K3_STRIDE + ((10 + col) % K3_NKC) * 16) = zero4;
    *reinterpret_cast<uint4*>(lds + col * K3_STRIDE + ((11 + col) % K3_NKC) * 16) = zero4;
  }

  bf16x8 wf[5][3];
#pragma unroll
  for (int mt = 0; mt < 5; ++mt)
#pragma unroll
    for (int c = 0; c < 3; ++c)
      wf[mt][c] = *reinterpret_cast<const bf16x8*>(
          Wlinbf + (mt * 16 + lr) * 96 + c * 32 + lg * 8);
  float bias[5];
#pragma unroll
  for (int mt = 0; mt < 5; ++mt) bias[mt] = b_lin[mt * 16 + lr];

  float sqp[5] = {0.f, 0.f, 0.f, 0.f, 0.f};

#pragma unroll
  for (int t = 0; t < K3_TPB; ++t) {
    const int s0 = (tile0 + t) * 256;
    twrite(lds, K3_STRIDE, K3_NKC, rrA, kcA, cgA);
    if (hasB) twrite(lds, K3_STRIDE, K3_NKC, rrB, kcB, cgB);
    __syncthreads();
    if (t + 1 < K3_TPB) {
      LOAD(s0 + 256, rrA, kcA, cgA);
      if (hasB) LOAD(s0 + 256, rrB, kcB, cgB);
    }

#pragma unroll
    for (int p = 0; p < 2; ++p) {
      f32x4 acc2[2][5];
#pragma unroll
      for (int nth = 0; nth < 2; ++nth) {
        const int nt = p * 2 + nth;
        const int col = wv * 64 + nt * 16 + lr;
        bf16x8 xa[3];
#pragma unroll
        for (int c = 0; c < 3; ++c) {
          const int kc = c * 4 + lg;
          xa[c] = *reinterpret_cast<const bf16x8*>(
              lds + col * K3_STRIDE + ((kc + col) % K3_NKC) * 16);
        }
#pragma unroll
        for (int mt = 0; mt < 5; ++mt)
          acc2[nth][mt] = (f32x4){bias[mt], bias[mt], bias[mt], bias[mt]};
#pragma unroll
        for (int c = 0; c < 3; ++c)
#pragma unroll
          for (int mt = 0; mt < 5; ++mt)
            acc2[nth][mt] = __builtin_amdgcn_mfma_f32_16x16x32_bf16(
                xa[c], wf[mt][c], acc2[nth][mt], 0, 0, 0);
#pragma unroll
        for (int mt = 0; mt < 5; ++mt)
#pragma unroll
          for (int j = 0; j < 4; ++j)
            sqp[mt] = fmaf(acc2[nth][mt][j], acc2[nth][mt][j], sqp[mt]);
      }
#pragma unroll
      for (int nth = 0; nth < 2; ++nth)
#pragma unroll
        for (int mt = 0; mt < 5; ++mt)
          *reinterpret_cast<ushort4*>(
              &cbuf[(mt * 16 + lr) * CB_S + wv * 32 + nth * 16 + lg * 4]) =
              pack4(acc2[nth][mt]);
      __syncthreads();
#pragma unroll
      for (int i = 0; i < 5; ++i) {
        const int q = i * 256 + tid;
        const int row = q >> 4, cch = q & 15;
        uint4 v = *reinterpret_cast<const uint4*>(&cbuf[row * CB_S + cch * 8]);
        const int u = c2 * TG_ + row;
        const int gcol = s0 + (cch >> 2) * 64 + p * 32 + (cch & 3) * 8;
        *reinterpret_cast<uint4*>(z + (size_t)u * HW_ + gcol) = v;
      }
      __syncthreads();
    }
  }

  if (c2 < 16) {
#pragma unroll
    for (int mt = 0; mt < 5; ++mt) {
      float v = sqp[mt];
      v += __shfl_xor(v, 16);
      v += __shfl_xor(v, 32);
      if (lane < 16)
        atomicAdd(&ssq[c2 * TG_ + mt * 16 + lane], v);
    }
  }
}

// ================ K5 (MFMA): Gpart = partial QK^T, 16 chunks of 1024 s ================
__global__ __launch_bounds__(256) void k5_mfma(
    const bf16* __restrict__ zws, float* __restrict__ Gpartws) {
  __shared__ __align__(16) float gbuf[2][TG_ * TG_];   // 51.2 KiB
  const int chunk = blockIdx.x, h = blockIdx.y, b = blockIdx.z;
  const bf16* z = zws + (size_t)b * C3_ * THW_;
  float* Gpart = Gpartws + (size_t)b * 819200;
  const int tid = threadIdx.x;
  const int lane = tid & 63, wv = tid >> 6;
  const int lr = lane & 15, lg = lane >> 4;

  const bf16* qbase = z + (size_t)(h * TG_) * HW_;
  const bf16* kbase = z + (size_t)((8 + h) * TG_) * HW_;

  f32x4 acc[5][5];
#pragma unroll
  for (int a = 0; a < 5; ++a)
#pragma unroll
    for (int b2 = 0; b2 < 5; ++b2) acc[a][b2] = (f32x4){0.f, 0.f, 0.f, 0.f};

  const int s0 = chunk * 1024 + wv * 256;
  for (int s = s0; s < s0 + 256; s += 32) {
    bf16x8 qa[5], kb[5];
#pragma unroll
    for (int a = 0; a < 5; ++a)
      qa[a] = *reinterpret_cast<const bf16x8*>(qbase + (size_t)(a * 16 + lr) * HW_ + s + lg * 8);
#pragma unroll
    for (int a = 0; a < 5; ++a)
      kb[a] = *reinterpret_cast<const bf16x8*>(kbase + (size_t)(a * 16 + lr) * HW_ + s + lg * 8);
#pragma unroll
    for (int a = 0; a < 5; ++a)
#pragma unroll
      for (int b2 = 0; b2 < 5; ++b2)
        acc[a][b2] = __builtin_amdgcn_mfma_f32_16x16x32_bf16(qa[a], kb[b2], acc[a][b2], 0, 0, 0);
  }

  if (wv == 1 || wv == 3) {
    float* dst = gbuf[wv >> 1];
#pragma unroll
    for (int a = 0; a < 5; ++a)
#pragma unroll
      for (int b2 = 0; b2 < 5; ++b2)
#pragma unroll
        for (int j = 0; j < 4; ++j)
          dst[(a * 16 + lg * 4 + j) * TG_ + b2 * 16 + lr] = acc[a][b2][j];
  }
  __syncthreads();
  if (wv == 0 || wv == 2) {
    const float* srcb = gbuf[wv >> 1];
#pragma unroll
    for (int a = 0; a < 5; ++a)
#pragma unroll
      for (int b2 = 0; b2 < 5; ++b2)
#pragma unroll
        for (int j = 0; j < 4; ++j)
          acc[a][b2][j] += srcb[(a * 16 + lg * 4 + j) * TG_ + b2 * 16 + lr];
  }
  __syncthreads();
  if (wv == 2) {
#pragma unroll
    for (int a = 0; a < 5; ++a)
#pragma unroll
      for (int b2 = 0; b2 < 5; ++b2)
#pragma unroll
        for (int j = 0; j < 4; ++j)
          gbuf[0][(a * 16 + lg * 4 + j) * TG_ + b2 * 16 + lr] = acc[a][b2][j];
  }
  __syncthreads();
  if (wv == 0) {
    float* gp = Gpart + ((size_t)chunk * 8 + h) * TG_ * TG_;
#pragma unroll
    for (int a = 0; a < 5; ++a)
#pragma unroll
      for (int b2 = 0; b2 < 5; ++b2)
#pragma unroll
        for (int j = 0; j < 4; ++j) {
          const int i = a * 16 + lg * 4 + j, jj = b2 * 16 + lr;
          gp[i * TG_ + jj] = acc[a][b2][j] + gbuf[0][i * TG_ + jj];
        }
  }
}

// ================ K6: softmax -> bf16 attn [80][96] padded, batch in grid.y ================
__global__ __launch_bounds__(128) void k6_softmax(
    const float* __restrict__ Gpartws, const float* __restrict__ ssqws,
    const float* __restrict__ temp, bf16* __restrict__ attnbfws) {
  __shared__ float red[128];
  __shared__ float smax, ssum;
  const int b = blockIdx.y;
  const float* Gpart = Gpartws + (size_t)b * 819200;
  const float* ssq = ssqws + b * 1280;
  bf16* attnbf = attnbfws + (size_t)b * NH_ * TG_ * 96;
  int h = blockIdx.x / TG_, i = blockIdx.x % TG_;
  int j = threadIdx.x;
  float logit = -1e30f;
  if (j < TG_) {
    float g = 0.f;
    for (int c = 0; c < 16; ++c)
      g += Gpart[(((size_t)c * 8 + h) * TG_ + i) * TG_ + j];
    float nq = ssq[h * TG_ + i];
    float nk = ssq[(8 + h) * TG_ + j];
    float sq = 1.f / fmaxf(sqrtf(nq), 1e-12f);
    float sk = 1.f / fmaxf(sqrtf(nk), 1e-12f);
    logit = g * sq * sk * temp[h];
  }
  red[j] = logit;
  __syncthreads();
  if (j == 0) {
    float m = -1e30f;
    for (int x2 = 0; x2 < TG_; ++x2) m = fmaxf(m, red[x2]);
    smax = m;
  }
  __syncthreads();
  float e = (j < TG_) ? expf(logit - smax) : 0.f;
  red[j] = e;
  __syncthreads();
  if (j == 0) {
    float s = 0.f;
    for (int x2 = 0; x2 < TG_; ++x2) s += red[x2];
    ssum = s;
  }
  __syncthreads();
  if (j < 96)
    attnbf[((size_t)h * TG_ + i) * 96 + j] =
        __float2bfloat16(j < TG_ ? e / ssum : 0.f);
}

// ================ K7a (MFMA): att_out = attn @ v, TPB=2 pipeline + C-shuffle ================
#define K7A_TPB 2
__global__ __launch_bounds__(256) void k7a_mfma(
    const bf16* __restrict__ zws, const bf16* __restrict__ attnbfws,
    bf16* __restrict__ att_outws) {
  __shared__ __align__(16) char lds[256 * K3_STRIDE];   // 53,248 B
  __shared__ __align__(16) ushort cbuf[80 * CB_S];      // 21,760 B
  const int tid = threadIdx.x;
  const int tile0 = blockIdx.x * K7A_TPB;
  const int h = blockIdx.y;
  const int b = blockIdx.z;
  const bf16* z = zws + (size_t)b * C3_ * THW_;
  const bf16* attnbf = attnbfws + (size_t)b * NH_ * TG_ * 96;
  bf16* att_out = att_outws + (size_t)b * NH_ * TG_ * HW_;
  const int voff = (16 + h) * TG_;

  const int lane = tid & 63, wv = tid >> 6;
  const int lr = lane & 15, lg = lane >> 4;

  const int kcA = tid >> 5, cgA = tid & 31;
  const bool hasB = (tid & 3) == 0;
  const int qB = tid >> 2;
  const int kcB = 8 + (qB >> 5), cgB = qB & 31;

  uint rrA[8][4], rrB[8][4];
  auto LOAD = [&](int s0, uint r[8][4], int kc, int cg) {
#pragma unroll
    for (int e = 0; e < 8; ++e) {
      uint4 raw = *reinterpret_cast<const uint4*>(
          z + (size_t)(voff + kc * 8 + e) * HW_ + s0 + cg * 8);
      r[e][0] = raw.x; r[e][1] = raw.y; r[e][2] = raw.z; r[e][3] = raw.w;
    }
  };

  LOAD(tile0 * 256, rrA, kcA, cgA);
  if (hasB) LOAD(tile0 * 256, rrB, kcB, cgB);
  {
    const int col = tid;
    const uint4 zero4 = {0, 0, 0, 0};
    *reinterpret_cast<uint4*>(lds + col * K3_STRIDE + ((10 + col) % K3_NKC) * 16) = zero4;
    *reinterpret_cast<uint4*>(lds + col * K3_STRIDE + ((11 + col) % K3_NKC) * 16) = zero4;
  }

  bf16x8 wf[5][3];
#pragma unroll
  for (int mt = 0; mt < 5; ++mt)
#pragma unroll
    for (int c = 0; c < 3; ++c)
      wf[mt][c] = *reinterpret_cast<const bf16x8*>(
          attnbf + ((size_t)h * TG_ + mt * 16 + lr) * 96 + c * 32 + lg * 8);

#pragma unroll
  for (int t = 0; t < K7A_TPB; ++t) {
    const int s0 = (tile0 + t) * 256;
    twrite(lds, K3_STRIDE, K3_NKC, rrA, kcA, cgA);
    if (hasB) twrite(lds, K3_STRIDE, K3_NKC, rrB, kcB, cgB);
    __syncthreads();
    if (t + 1 < K7A_TPB) {
      LOAD(s0 + 256, rrA, kcA, cgA);
      if (hasB) LOAD(s0 + 256, rrB, kcB, cgB);
    }

#pragma unroll
    for (int p = 0; p < 2; ++p) {
      f32x4 acc2[2][5];
#pragma unroll
      for (int nth = 0; nth < 2; ++nth) {
        const int nt = p * 2 + nth;
        const int col = wv * 64 + nt * 16 + lr;
        bf16x8 xa[3];
#pragma unroll
        for (int c = 0; c < 3; ++c) {
          const int kc = c * 4 + lg;
          xa[c] = *reinterpret_cast<const bf16x8*>(
              lds + col * K3_STRIDE + ((kc + col) % K3_NKC) * 16);
        }
#pragma unroll
        for (int mt = 0; mt < 5; ++mt) acc2[nth][mt] = (f32x4){0.f, 0.f, 0.f, 0.f};
#pragma unroll
        for (int c = 0; c < 3; ++c)
#pragma unroll
          for (int mt = 0; mt < 5; ++mt)
            acc2[nth][mt] = __builtin_amdgcn_mfma_f32_16x16x32_bf16(
                xa[c], wf[mt][c], acc2[nth][mt], 0, 0, 0);
      }
#pragma unroll
      for (int nth = 0; nth < 2; ++nth)
#pragma unroll
        for (int mt = 0; mt < 5; ++mt)
          *reinterpret_cast<ushort4*>(
              &cbuf[(mt * 16 + lr) * CB_S + wv * 32 + nth * 16 + lg * 4]) =
              pack4(acc2[nth][mt]);
      __syncthreads();
#pragma unroll
      for (int i = 0; i < 5; ++i) {
        const int q = i * 256 + tid;
        const int row = q >> 4, cch = q & 15;
        uint4 v = *reinterpret_cast<const uint4*>(&cbuf[row * CB_S + cch * 8]);
        const int u = h * TG_ + row;
        const int gcol = s0 + (cch >> 2) * 64 + p * 32 + (cch & 3) * 8;
        *reinterpret_cast<uint4*>(att_out + (size_t)u * HW_ + gcol) = v;
      }
      __syncthreads();
    }
  }
}

// ================ K7b (MFMA): out = W_out @ regroup(att_out), TPB=2 pipeline ================
#define K1_NKC 10
#define K1_STRIDE 160
#define K7B_TPB 2
__global__ __launch_bounds__(256) void k7b_mfma(
    const bf16* __restrict__ att_outws, const bf16* __restrict__ Woutbf,
    float* __restrict__ out) {
  __shared__ __align__(16) char lds[256 * K1_STRIDE];   // 40 KiB
  const int tid = threadIdx.x;
  const int tile0 = blockIdx.x * K7B_TPB;
  const int b = blockIdx.y;
  const bf16* att_out = att_outws + (size_t)b * NH_ * TG_ * HW_;
  float* outb = out + (size_t)b * C_ * THW_;
  const int t_ = tile0 >> 6;
  const int lane = tid & 63, wv = tid >> 6;
  const int lr = lane & 15, lg = lane >> 4;

  const int kcA = tid >> 5, cgA = tid & 31;
  uint rrA[8][4];
  auto LOAD = [&](int tile, uint r[8][4]) {
    const int sb0 = (tile * 256) & (HW_ - 1);
#pragma unroll
    for (int e = 0; e < 8; ++e) {
      const int row = kcA * TG_ + e * T_ + t_;
      uint4 raw = *reinterpret_cast<const uint4*>(
          att_out + (size_t)row * HW_ + sb0 + cgA * 8);
      r[e][0] = raw.x; r[e][1] = raw.y; r[e][2] = raw.z; r[e][3] = raw.w;
    }
  };

  LOAD(tile0, rrA);

  bf16x8 wf[4][2];
#pragma unroll
  for (int mt = 0; mt < 4; ++mt)
#pragma unroll
    for (int c = 0; c < 2; ++c)
      wf[mt][c] = *reinterpret_cast<const bf16x8*>(
          Woutbf + (mt * 16 + lr) * 64 + c * 32 + lg * 8);

#pragma unroll
  for (int t = 0; t < K7B_TPB; ++t) {
    const int n0 = (tile0 + t) * 256;
    twrite(lds, K1_STRIDE, K1_NKC, rrA, kcA, cgA);
    __syncthreads();
    if (t + 1 < K7B_TPB) LOAD(tile0 + t + 1, rrA);

    for (int nt = 0; nt < 4; ++nt) {
      const int col = wv * 64 + nt * 16 + lr;
      bf16x8 xa[2];
#pragma unroll
      for (int c = 0; c < 2; ++c) {
        const int kc = c * 4 + lg;
        xa[c] = *reinterpret_cast<const bf16x8*>(
            lds + col * K1_STRIDE + ((kc + col) % K1_NKC) * 16);
      }
      f32x4 acc[4];
#pragma unroll
      for (int mt = 0; mt < 4; ++mt) acc[mt] = (f32x4){0.f, 0.f, 0.f, 0.f};
#pragma unroll
      for (int c = 0; c < 2; ++c)
#pragma unroll
        for (int mt = 0; mt < 4; ++mt)
          acc[mt] = __builtin_amdgcn_mfma_f32_16x16x32_bf16(xa[c], wf[mt][c], acc[mt], 0, 0, 0);
      const int nb = n0 + wv * 64 + nt * 16 + lg * 4;
#pragma unroll
      for (int mt = 0; mt < 4; ++mt) {
        const int o = mt * 16 + lr;
        *reinterpret_cast<float4*>(outb + (size_t)o * THW_ + nb) =
            (float4){acc[mt][0], acc[mt][1], acc[mt][2], acc[mt][3]};
      }
    }
    __syncthreads();
  }
}

extern "C" void kernel_launch(void* const* d_in, const int* in_sizes, int n_in,
                              void* d_out, int out_size, void* d_ws, size_t ws_size,
                              hipStream_t stream) {
  const float* x    = (const float*)d_in[0];
  const float* W1   = (const float*)d_in[1];
  const float* Wdw  = (const float*)d_in[2];
  const float* Wlin = (const float*)d_in[3];
  const float* blin = (const float*)d_in[4];
  const float* temp = (const float*)d_in[5];
  const float* Wout = (const float*)d_in[6];
  float* out = (float*)d_out;

  const size_t NY = (size_t)C3_ * THW_;          // 31,457,280 elems (60MB bf16)
  char* ws = (char*)d_ws;
  bf16* y1z = (bf16*)ws;                          // y1[b] = z[b] = y1z + b*NY
  bf16* y2  = (bf16*)(ws + 4 * NY);               // y2[b]
  char* E   = ws + 8 * NY;                        // extras base
  float* Gpart  = (float*)E;                      // 2 x 3,276,800 B (16 chunks)
  bf16* attnbf  = (bf16*)(E + 6553600);           // 2 x 245,760 B
  bf16* att_out = (bf16*)(E + 7045120);           // 2 x 20,971,520 B
  float* ssq    = (float*)(E + 48988160);         // 10,240 B
  bf16* W1bf    = (bf16*)(E + 48998400);          // 24,576 B
  bf16* Wlinbf  = (bf16*)(E + 49022976);          // 15,360 B
  bf16* Woutbf  = (bf16*)(E + 49038336);          // 8,192 B

  kprep<<<94, 256, 0, stream>>>(W1, Wlin, Wout, W1bf, Wlinbf, Woutbf);
  hipMemsetAsync(ssq, 0, 2 * 1280 * sizeof(float), stream);
  k1_mfma<<<dim3(THW_ / 128, 2, 2), 256, 0, stream>>>(x, W1bf, y1z);
  k2_dw<<<dim3(C3_ * T_ * 4, 2), 256, 0, stream>>>(y1z, Wdw, y2);
  k3_mfma<<<dim3(HW_ / 256 / K3_TPB, C2_, 2), 256, 0, stream>>>(y2, Wlinbf, blin, y1z, ssq);
  k5_mfma<<<dim3(16, NH_, 2), 256, 0, stream>>>(y1z, Gpart);
  k6_softmax<<<dim3(NH_ * TG_, 2), 128, 0, stream>>>(Gpart, ssq, temp, attnbf);
  k7a_mfma<<<dim3(HW_ / 256 / K7A_TPB, NH_, 2), 256, 0, stream>>>(y1z, attnbf, att_out);
  k7b_mfma<<<dim3(THW_ / 256 / K7B_TPB, 2), 256, 0, stream>>>(att_out, Woutbf, out);
}

// Round 17
// 256.571 us; speedup vs baseline: 1.0570x; 1.0570x over previous
//
#include <hip/hip_runtime.h>
#include <hip/hip_bf16.h>

#define C_  64
#define C3_ 192
#define T_  10
#define H_  128
#define W_  128
#define HW_ 16384        // H_*W_
#define THW_ 163840      // T_*HW_
#define NH_ 8
#define C2_ 24
#define TG_ 80           // t * SHUFFLE_G

typedef __hip_bfloat16 bf16;
typedef __attribute__((ext_vector_type(8))) short bf16x8;
typedef __attribute__((ext_vector_type(4))) float f32x4;

__device__ __forceinline__ float bf2f(bf16 v) { return __bfloat162float(v); }

__device__ __forceinline__ ushort f2bf_s(float f) {
  bf16 h = __float2bfloat16(f);
  union { bf16 b; ushort s; } u; u.b = h; return u.s;
}

__device__ __forceinline__ ushort4 pack4(f32x4 a) {
  ushort4 p;
  p.x = f2bf_s(a[0]); p.y = f2bf_s(a[1]); p.z = f2bf_s(a[2]); p.w = f2bf_s(a[3]);
  return p;
}

__device__ __forceinline__ uint pack2lo(uint x, uint y) { return (x & 0xffffu) | (y << 16); }
__device__ __forceinline__ uint pack2hi(uint x, uint y) { return (x >> 16) | (y & 0xffff0000u); }

// transpose 8x8 ushort block (rr[e][d] raw dwords) -> 8 k-contig uint4, write to lds
__device__ __forceinline__ void twrite(char* lds, int stride, int nkc,
                                       uint r[8][4], int kc, int cg) {
#pragma unroll
  for (int j = 0; j < 8; ++j) {
    const int d = j >> 1;
    uint4 o;
    if (j & 1) {
      o.x = pack2hi(r[0][d], r[1][d]); o.y = pack2hi(r[2][d], r[3][d]);
      o.z = pack2hi(r[4][d], r[5][d]); o.w = pack2hi(r[6][d], r[7][d]);
    } else {
      o.x = pack2lo(r[0][d], r[1][d]); o.y = pack2lo(r[2][d], r[3][d]);
      o.z = pack2lo(r[4][d], r[5][d]); o.w = pack2lo(r[6][d], r[7][d]);
    }
    const int col = cg * 8 + j;
    const int rr = (kc + col) % nkc;
    *reinterpret_cast<uint4*>(lds + col * stride + rr * 16) = o;
  }
}

// ================ KPREP: one-time weight conversion + ssq zeroing ================
__global__ __launch_bounds__(256) void kprep(
    const float* __restrict__ W1, const float* __restrict__ W_lin,
    const float* __restrict__ W_out,
    bf16* __restrict__ W1bf, bf16* __restrict__ Wlinbf, bf16* __restrict__ Woutbf,
    float* __restrict__ ssq) {
  const int idx = blockIdx.x * 256 + threadIdx.x;
  if (idx < 2560) ssq[idx] = 0.f;
  if (idx < 12288) {
    W1bf[idx] = __float2bfloat16(W1[idx]);
  } else if (idx < 12288 + 7680) {
    const int i = idx - 12288;
    const int row = i / 96, col = i - row * 96;
    Wlinbf[i] = __float2bfloat16(col < 80 ? W_lin[row * 80 + col] : 0.f);
  } else if (idx < 12288 + 7680 + 4096) {
    const int i = idx - 12288 - 7680;
    Woutbf[i] = __float2bfloat16(W_out[i]);
  }
}

// ================ K1 (MFMA): y1 = W1 @ x, DMA double-buffer + source-XOR swizzle ================
#define K1_TPB 4
__global__ __launch_bounds__(256) void k1_mfma(
    const float* __restrict__ x, const bf16* __restrict__ W1bf,
    bf16* __restrict__ y1ws) {
  __shared__ __align__(16) float xs[2][64 * 128];   // 65,536 B
  const int tid = threadIdx.x;
  const int lane = tid & 63, wv = tid >> 6;
  const int lr = lane & 15, lg = lane >> 4;
  const int mh = blockIdx.y;
  const int b = blockIdx.z;
  const float* xb = x + (size_t)b * C_ * THW_;
  bf16* y1 = y1ws + (size_t)b * C3_ * THW_;
  const int tile0 = blockIdx.x * K1_TPB;

  const int ro = lane >> 5, colo = (lane & 31) * 4;
  auto STAGE = [&](int buf, int tIdx) {
    const int n0 = tIdx * 128;
#pragma unroll
    for (int i = 0; i < 8; ++i) {
      const int row = wv * 16 + i * 2;
      const int rr = row + ro;
      const int sw = (rr >> 3) & 1;
      const float* gsrc = xb + (size_t)rr * THW_ + n0 + (colo ^ (sw << 4));
      __builtin_amdgcn_global_load_lds(
          (const __attribute__((address_space(1))) void*)gsrc,
          (__attribute__((address_space(3))) void*)&xs[buf][row * 128],
          16, 0, 0);
    }
  };

  STAGE(0, tile0);

  bf16x8 wf[6][2];
#pragma unroll
  for (int mt = 0; mt < 6; ++mt)
#pragma unroll
    for (int c = 0; c < 2; ++c) {
      const int row = mh * 96 + mt * 16 + lr;
      wf[mt][c] = *reinterpret_cast<const bf16x8*>(W1bf + row * 64 + c * 32 + lg * 8);
    }
  __syncthreads();

  int buf = 0;
  for (int t = 0; t < K1_TPB; ++t) {
    if (t + 1 < K1_TPB) STAGE(buf ^ 1, tile0 + t + 1);
    const int n0 = (tile0 + t) * 128;
#pragma unroll
    for (int nt = 0; nt < 2; ++nt) {
      const int col = wv * 32 + nt * 16 + lr;
      const int col2 = col ^ ((lg & 1) << 4);           // un-swizzle at read
      bf16x8 xa[2];
#pragma unroll
      for (int c = 0; c < 2; ++c) {
        const float* base = &xs[buf][(c * 32 + lg * 8) * 128 + col2];
        bf16x8 f;
#pragma unroll
        for (int e = 0; e < 8; ++e) f[e] = f2bf_s(base[e * 128]);
        xa[c] = f;
      }
      f32x4 acc[6];
#pragma unroll
      for (int mt = 0; mt < 6; ++mt) acc[mt] = (f32x4){0.f, 0.f, 0.f, 0.f};
#pragma unroll
      for (int c = 0; c < 2; ++c)
#pragma unroll
        for (int mt = 0; mt < 6; ++mt)
          acc[mt] = __builtin_amdgcn_mfma_f32_16x16x32_bf16(xa[c], wf[mt][c], acc[mt], 0, 0, 0);
      const int nb = n0 + wv * 32 + nt * 16 + lg * 4;
#pragma unroll
      for (int mt = 0; mt < 6; ++mt) {
        const int o = mh * 96 + mt * 16 + lr;
        *reinterpret_cast<ushort4*>(y1 + (size_t)o * THW_ + nb) = pack4(acc[mt]);
      }
    }
    __syncthreads();
    buf ^= 1;
  }
}

// ================ K2: depthwise 3x3, 32x128 tile, batch in grid.y ================
__global__ __launch_bounds__(256) void k2_dw(
    const bf16* __restrict__ y1ws, const float* __restrict__ Wdw,
    bf16* __restrict__ y2ws) {
  __shared__ float tile[34][132];
  const int tid = threadIdx.x;
  const int blk = blockIdx.x;
  const int b = blockIdx.y;
  const bf16* y1 = y1ws + (size_t)b * C3_ * THW_;
  bf16* y2 = y2ws + (size_t)b * C3_ * THW_;
  const int hs = (blk & 3) * 32;
  const int rest = blk >> 2;
  const int t = rest % T_;
  const int o = rest / T_;
  const bf16* src = y1 + ((size_t)o * T_ + t) * HW_;

  if (tid < 68) {
    const int r = tid >> 1, side = tid & 1;
    tile[r][side ? 129 : 0] = 0.f;
  }
  {
    const int rr = tid >> 5, c4 = (tid & 31) * 4;
#pragma unroll
    for (int p = 0; p < 5; ++p) {
      const int r = p * 8 + rr;
      if (r < 34) {
        const int hh = hs - 1 + r;
        float e0 = 0.f, e1 = 0.f, e2 = 0.f, e3 = 0.f;
        if (hh >= 0 && hh < H_) {
          uint2 raw = *reinterpret_cast<const uint2*>(src + hh * W_ + c4);
          e0 = __uint_as_float(raw.x << 16);
          e1 = __uint_as_float(raw.x & 0xffff0000u);
          e2 = __uint_as_float(raw.y << 16);
          e3 = __uint_as_float(raw.y & 0xffff0000u);
        }
        tile[r][1 + c4]     = e0;
        tile[r][1 + c4 + 1] = e1;
        tile[r][1 + c4 + 2] = e2;
        tile[r][1 + c4 + 3] = e3;
      }
    }
  }
  __syncthreads();

  float kk[9];
#pragma unroll
  for (int i = 0; i < 9; ++i) kk[i] = Wdw[o * 9 + i];

  bf16* dst = y2 + ((size_t)o * T_ + t) * HW_;
  const int w = tid & 127;
  const int r0 = (tid >> 7) * 16;

  float a[3][3];
#pragma unroll
  for (int ky = 0; ky < 3; ++ky)
#pragma unroll
    for (int kx = 0; kx < 3; ++kx) a[ky][kx] = tile[r0 + ky][w + kx];

#pragma unroll
  for (int q = 0; q < 16; ++q) {
    float acc = 0.f;
#pragma unroll
    for (int ky = 0; ky < 3; ++ky)
#pragma unroll
      for (int kx = 0; kx < 3; ++kx)
        acc = fmaf(kk[ky * 3 + kx], a[ky][kx], acc);
    dst[(hs + r0 + q) * W_ + w] = __float2bfloat16(acc);
    if (q < 15) {
#pragma unroll
      for (int kx = 0; kx < 3; ++kx) {
        a[0][kx] = a[1][kx];
        a[1][kx] = a[2][kx];
        a[2][kx] = tile[r0 + q + 3][w + kx];
      }
    }
  }
}

// ================ K3 (MFMA): z = W_lin @ shuffled(y2) + b, fused ssq, TPB pipeline + C-shuffle ================
#define K3_NKC 13
#define K3_STRIDE 208
#define K3_TPB 4
#define CB_S 136
__global__ __launch_bounds__(256) void k3_mfma(
    const bf16* __restrict__ y2ws, const bf16* __restrict__ Wlinbf,
    const float* __restrict__ b_lin, bf16* __restrict__ zws,
    float* __restrict__ ssqws) {
  __shared__ __align__(16) char lds[256 * K3_STRIDE];   // 53,248 B
  __shared__ __align__(16) ushort cbuf[80 * CB_S];      // 21,760 B
  const int tid = threadIdx.x;
  const int tile0 = blockIdx.x * K3_TPB;
  const int c2 = blockIdx.y;
  const int b = blockIdx.z;
  const bf16* y2 = y2ws + (size_t)b * C3_ * THW_;
  bf16* z = zws + (size_t)b * C3_ * THW_;
  float* ssq = ssqws + b * 1280;

  const int lane = tid & 63, wv = tid >> 6;
  const int lr = lane & 15, lg = lane >> 4;

  const int kcA = tid >> 5, cgA = tid & 31;
  const bool hasB = (tid & 3) == 0;
  const int qB = tid >> 2;
  const int kcB = 8 + (qB >> 5), cgB = qB & 31;

  uint rrA[8][4], rrB[8][4];
  auto LOAD = [&](int s0, uint r[8][4], int kc, int cg) {
#pragma unroll
    for (int e = 0; e < 8; ++e) {
      const int k = kc * 8 + e;
      const int c1 = (k * 205) >> 11;        // k/10
      const int tt = k - c1 * 10;
      uint4 raw = *reinterpret_cast<const uint4*>(
          y2 + ((size_t)((c1 * C2_ + c2) * T_ + tt)) * HW_ + s0 + cg * 8);
      r[e][0] = raw.x; r[e][1] = raw.y; r[e][2] = raw.z; r[e][3] = raw.w;
    }
  };

  LOAD(tile0 * 256, rrA, kcA, cgA);
  if (hasB) LOAD(tile0 * 256, rrB, kcB, cgB);
  {
    const int col = tid;
    const uint4 zero4 = {0, 0, 0, 0};
    *reinterpret_cast<uint4*>(lds + col * K3_STRIDE + ((10 + col) % K3_NKC) * 16) = zero4;
    *reinterpret_cast<uint4*>(lds + col * K3_STRIDE + ((11 + col) % K3_NKC) * 16) = zero4;
  }

  bf16x8 wf[5][3];
#pragma unroll
  for (int mt = 0; mt < 5; ++mt)
#pragma unroll
    for (int c = 0; c < 3; ++c)
      wf[mt][c] = *reinterpret_cast<const bf16x8*>(
          Wlinbf + (mt * 16 + lr) * 96 + c * 32 + lg * 8);
  float bias[5];
#pragma unroll
  for (int mt = 0; mt < 5; ++mt) bias[mt] = b_lin[mt * 16 + lr];

  float sqp[5] = {0.f, 0.f, 0.f, 0.f, 0.f};

#pragma unroll
  for (int t = 0; t < K3_TPB; ++t) {
    const int s0 = (tile0 + t) * 256;
    twrite(lds, K3_STRIDE, K3_NKC, rrA, kcA, cgA);
    if (hasB) twrite(lds, K3_STRIDE, K3_NKC, rrB, kcB, cgB);
    __syncthreads();
    if (t + 1 < K3_TPB) {
      LOAD(s0 + 256, rrA, kcA, cgA);
      if (hasB) LOAD(s0 + 256, rrB, kcB, cgB);
    }

#pragma unroll
    for (int p = 0; p < 2; ++p) {
      f32x4 acc2[2][5];
#pragma unroll
      for (int nth = 0; nth < 2; ++nth) {
        const int nt = p * 2 + nth;
        const int col = wv * 64 + nt * 16 + lr;
        bf16x8 xa[3];
#pragma unroll
        for (int c = 0; c < 3; ++c) {
          const int kc = c * 4 + lg;
          xa[c] = *reinterpret_cast<const bf16x8*>(
              lds + col * K3_STRIDE + ((kc + col) % K3_NKC) * 16);
        }
#pragma unroll
        for (int mt = 0; mt < 5; ++mt)
          acc2[nth][mt] = (f32x4){bias[mt], bias[mt], bias[mt], bias[mt]};
#pragma unroll
        for (int c = 0; c < 3; ++c)
#pragma unroll
          for (int mt = 0; mt < 5; ++mt)
            acc2[nth][mt] = __builtin_amdgcn_mfma_f32_16x16x32_bf16(
                xa[c], wf[mt][c], acc2[nth][mt], 0, 0, 0);
#pragma unroll
        for (int mt = 0; mt < 5; ++mt)
#pragma unroll
          for (int j = 0; j < 4; ++j)
            sqp[mt] = fmaf(acc2[nth][mt][j], acc2[nth][mt][j], sqp[mt]);
      }
#pragma unroll
      for (int nth = 0; nth < 2; ++nth)
#pragma unroll
        for (int mt = 0; mt < 5; ++mt)
          *reinterpret_cast<ushort4*>(
              &cbuf[(mt * 16 + lr) * CB_S + wv * 32 + nth * 16 + lg * 4]) =
              pack4(acc2[nth][mt]);
      __syncthreads();
#pragma unroll
      for (int i = 0; i < 5; ++i) {
        const int q = i * 256 + tid;
        const int row = q >> 4, cch = q & 15;
        uint4 v = *reinterpret_cast<const uint4*>(&cbuf[row * CB_S + cch * 8]);
        const int u = c2 * TG_ + row;
        const int gcol = s0 + (cch >> 2) * 64 + p * 32 + (cch & 3) * 8;
        *reinterpret_cast<uint4*>(z + (size_t)u * HW_ + gcol) = v;
      }
      __syncthreads();
    }
  }

  if (c2 < 16) {
#pragma unroll
    for (int mt = 0; mt < 5; ++mt) {
      float v = sqp[mt];
      v += __shfl_xor(v, 16);
      v += __shfl_xor(v, 32);
      if (lane < 16)
        atomicAdd(&ssq[c2 * TG_ + mt * 16 + lane], v);
    }
  }
}

// ================ K5 (MFMA): Gpart = partial QK^T, 16 chunks of 1024 s ================
__global__ __launch_bounds__(256) void k5_mfma(
    const bf16* __restrict__ zws, float* __restrict__ Gpartws) {
  __shared__ __align__(16) float gbuf[2][TG_ * TG_];   // 51.2 KiB
  const int chunk = blockIdx.x, h = blockIdx.y, b = blockIdx.z;
  const bf16* z = zws + (size_t)b * C3_ * THW_;
  float* Gpart = Gpartws + (size_t)b * 819200;
  const int tid = threadIdx.x;
  const int lane = tid & 63, wv = tid >> 6;
  const int lr = lane & 15, lg = lane >> 4;

  const bf16* qbase = z + (size_t)(h * TG_) * HW_;
  const bf16* kbase = z + (size_t)((8 + h) * TG_) * HW_;

  f32x4 acc[5][5];
#pragma unroll
  for (int a = 0; a < 5; ++a)
#pragma unroll
    for (int b2 = 0; b2 < 5; ++b2) acc[a][b2] = (f32x4){0.f, 0.f, 0.f, 0.f};

  const int s0 = chunk * 1024 + wv * 256;
  for (int s = s0; s < s0 + 256; s += 32) {
    bf16x8 qa[5], kb[5];
#pragma unroll
    for (int a = 0; a < 5; ++a)
      qa[a] = *reinterpret_cast<const bf16x8*>(qbase + (size_t)(a * 16 + lr) * HW_ + s + lg * 8);
#pragma unroll
    for (int a = 0; a < 5; ++a)
      kb[a] = *reinterpret_cast<const bf16x8*>(kbase + (size_t)(a * 16 + lr) * HW_ + s + lg * 8);
#pragma unroll
    for (int a = 0; a < 5; ++a)
#pragma unroll
      for (int b2 = 0; b2 < 5; ++b2)
        acc[a][b2] = __builtin_amdgcn_mfma_f32_16x16x32_bf16(qa[a], kb[b2], acc[a][b2], 0, 0, 0);
  }

  if (wv == 1 || wv == 3) {
    float* dst = gbuf[wv >> 1];
#pragma unroll
    for (int a = 0; a < 5; ++a)
#pragma unroll
      for (int b2 = 0; b2 < 5; ++b2)
#pragma unroll
        for (int j = 0; j < 4; ++j)
          dst[(a * 16 + lg * 4 + j) * TG_ + b2 * 16 + lr] = acc[a][b2][j];
  }
  __syncthreads();
  if (wv == 0 || wv == 2) {
    const float* srcb = gbuf[wv >> 1];
#pragma unroll
    for (int a = 0; a < 5; ++a)
#pragma unroll
      for (int b2 = 0; b2 < 5; ++b2)
#pragma unroll
        for (int j = 0; j < 4; ++j)
          acc[a][b2][j] += srcb[(a * 16 + lg * 4 + j) * TG_ + b2 * 16 + lr];
  }
  __syncthreads();
  if (wv == 2) {
#pragma unroll
    for (int a = 0; a < 5; ++a)
#pragma unroll
      for (int b2 = 0; b2 < 5; ++b2)
#pragma unroll
        for (int j = 0; j < 4; ++j)
          gbuf[0][(a * 16 + lg * 4 + j) * TG_ + b2 * 16 + lr] = acc[a][b2][j];
  }
  __syncthreads();
  if (wv == 0) {
    float* gp = Gpart + ((size_t)chunk * 8 + h) * TG_ * TG_;
#pragma unroll
    for (int a = 0; a < 5; ++a)
#pragma unroll
      for (int b2 = 0; b2 < 5; ++b2)
#pragma unroll
        for (int j = 0; j < 4; ++j) {
          const int i = a * 16 + lg * 4 + j, jj = b2 * 16 + lr;
          gp[i * TG_ + jj] = acc[a][b2][j] + gbuf[0][i * TG_ + jj];
        }
  }
}

// ================ K6: softmax -> bf16 attn [80][96] padded, batch in grid.y ================
__global__ __launch_bounds__(128) void k6_softmax(
    const float* __restrict__ Gpartws, const float* __restrict__ ssqws,
    const float* __restrict__ temp, bf16* __restrict__ attnbfws) {
  __shared__ float red[128];
  __shared__ float smax, ssum;
  const int b = blockIdx.y;
  const float* Gpart = Gpartws + (size_t)b * 819200;
  const float* ssq = ssqws + b * 1280;
  bf16* attnbf = attnbfws + (size_t)b * NH_ * TG_ * 96;
  int h = blockIdx.x / TG_, i = blockIdx.x % TG_;
  int j = threadIdx.x;
  float logit = -1e30f;
  if (j < TG_) {
    float g = 0.f;
    for (int c = 0; c < 16; ++c)
      g += Gpart[(((size_t)c * 8 + h) * TG_ + i) * TG_ + j];
    float nq = ssq[h * TG_ + i];
    float nk = ssq[(8 + h) * TG_ + j];
    float sq = 1.f / fmaxf(sqrtf(nq), 1e-12f);
    float sk = 1.f / fmaxf(sqrtf(nk), 1e-12f);
    logit = g * sq * sk * temp[h];
  }
  red[j] = logit;
  __syncthreads();
  if (j == 0) {
    float m = -1e30f;
    for (int x2 = 0; x2 < TG_; ++x2) m = fmaxf(m, red[x2]);
    smax = m;
  }
  __syncthreads();
  float e = (j < TG_) ? expf(logit - smax) : 0.f;
  red[j] = e;
  __syncthreads();
  if (j == 0) {
    float s = 0.f;
    for (int x2 = 0; x2 < TG_; ++x2) s += red[x2];
    ssum = s;
  }
  __syncthreads();
  if (j < 96)
    attnbf[((size_t)h * TG_ + i) * 96 + j] =
        __float2bfloat16(j < TG_ ? e / ssum : 0.f);
}

// ================ K7a (MFMA): att_out = attn @ v, TPB=2 pipeline + C-shuffle ================
#define K7A_TPB 2
__global__ __launch_bounds__(256) void k7a_mfma(
    const bf16* __restrict__ zws, const bf16* __restrict__ attnbfws,
    bf16* __restrict__ att_outws) {
  __shared__ __align__(16) char lds[256 * K3_STRIDE];   // 53,248 B
  __shared__ __align__(16) ushort cbuf[80 * CB_S];      // 21,760 B
  const int tid = threadIdx.x;
  const int tile0 = blockIdx.x * K7A_TPB;
  const int h = blockIdx.y;
  const int b = blockIdx.z;
  const bf16* z = zws + (size_t)b * C3_ * THW_;
  const bf16* attnbf = attnbfws + (size_t)b * NH_ * TG_ * 96;
  bf16* att_out = att_outws + (size_t)b * NH_ * TG_ * HW_;
  const int voff = (16 + h) * TG_;

  const int lane = tid & 63, wv = tid >> 6;
  const int lr = lane & 15, lg = lane >> 4;

  const int kcA = tid >> 5, cgA = tid & 31;
  const bool hasB = (tid & 3) == 0;
  const int qB = tid >> 2;
  const int kcB = 8 + (qB >> 5), cgB = qB & 31;

  uint rrA[8][4], rrB[8][4];
  auto LOAD = [&](int s0, uint r[8][4], int kc, int cg) {
#pragma unroll
    for (int e = 0; e < 8; ++e) {
      uint4 raw = *reinterpret_cast<const uint4*>(
          z + (size_t)(voff + kc * 8 + e) * HW_ + s0 + cg * 8);
      r[e][0] = raw.x; r[e][1] = raw.y; r[e][2] = raw.z; r[e][3] = raw.w;
    }
  };

  LOAD(tile0 * 256, rrA, kcA, cgA);
  if (hasB) LOAD(tile0 * 256, rrB, kcB, cgB);
  {
    const int col = tid;
    const uint4 zero4 = {0, 0, 0, 0};
    *reinterpret_cast<uint4*>(lds + col * K3_STRIDE + ((10 + col) % K3_NKC) * 16) = zero4;
    *reinterpret_cast<uint4*>(lds + col * K3_STRIDE + ((11 + col) % K3_NKC) * 16) = zero4;
  }

  bf16x8 wf[5][3];
#pragma unroll
  for (int mt = 0; mt < 5; ++mt)
#pragma unroll
    for (int c = 0; c < 3; ++c)
      wf[mt][c] = *reinterpret_cast<const bf16x8*>(
          attnbf + ((size_t)h * TG_ + mt * 16 + lr) * 96 + c * 32 + lg * 8);

#pragma unroll
  for (int t = 0; t < K7A_TPB; ++t) {
    const int s0 = (tile0 + t) * 256;
    twrite(lds, K3_STRIDE, K3_NKC, rrA, kcA, cgA);
    if (hasB) twrite(lds, K3_STRIDE, K3_NKC, rrB, kcB, cgB);
    __syncthreads();
    if (t + 1 < K7A_TPB) {
      LOAD(s0 + 256, rrA, kcA, cgA);
      if (hasB) LOAD(s0 + 256, rrB, kcB, cgB);
    }

#pragma unroll
    for (int p = 0; p < 2; ++p) {
      f32x4 acc2[2][5];
#pragma unroll
      for (int nth = 0; nth < 2; ++nth) {
        const int nt = p * 2 + nth;
        const int col = wv * 64 + nt * 16 + lr;
        bf16x8 xa[3];
#pragma unroll
        for (int c = 0; c < 3; ++c) {
          const int kc = c * 4 + lg;
          xa[c] = *reinterpret_cast<const bf16x8*>(
              lds + col * K3_STRIDE + ((kc + col) % K3_NKC) * 16);
        }
#pragma unroll
        for (int mt = 0; mt < 5; ++mt) acc2[nth][mt] = (f32x4){0.f, 0.f, 0.f, 0.f};
#pragma unroll
        for (int c = 0; c < 3; ++c)
#pragma unroll
          for (int mt = 0; mt < 5; ++mt)
            acc2[nth][mt] = __builtin_amdgcn_mfma_f32_16x16x32_bf16(
                xa[c], wf[mt][c], acc2[nth][mt], 0, 0, 0);
      }
#pragma unroll
      for (int nth = 0; nth < 2; ++nth)
#pragma unroll
        for (int mt = 0; mt < 5; ++mt)
          *reinterpret_cast<ushort4*>(
              &cbuf[(mt * 16 + lr) * CB_S + wv * 32 + nth * 16 + lg * 4]) =
              pack4(acc2[nth][mt]);
      __syncthreads();
#pragma unroll
      for (int i = 0; i < 5; ++i) {
        const int q = i * 256 + tid;
        const int row = q >> 4, cch = q & 15;
        uint4 v = *reinterpret_cast<const uint4*>(&cbuf[row * CB_S + cch * 8]);
        const int u = h * TG_ + row;
        const int gcol = s0 + (cch >> 2) * 64 + p * 32 + (cch & 3) * 8;
        *reinterpret_cast<uint4*>(att_out + (size_t)u * HW_ + gcol) = v;
      }
      __syncthreads();
    }
  }
}

// ================ K7b (MFMA): out = W_out @ regroup(att_out), TPB=2 pipeline ================
#define K1_NKC 10
#define K1_STRIDE 160
#define K7B_TPB 2
__global__ __launch_bounds__(256) void k7b_mfma(
    const bf16* __restrict__ att_outws, const bf16* __restrict__ Woutbf,
    float* __restrict__ out) {
  __shared__ __align__(16) char lds[256 * K1_STRIDE];   // 40 KiB
  const int tid = threadIdx.x;
  const int tile0 = blockIdx.x * K7B_TPB;
  const int b = blockIdx.y;
  const bf16* att_out = att_outws + (size_t)b * NH_ * TG_ * HW_;
  float* outb = out + (size_t)b * C_ * THW_;
  const int t_ = tile0 >> 6;
  const int lane = tid & 63, wv = tid >> 6;
  const int lr = lane & 15, lg = lane >> 4;

  const int kcA = tid >> 5, cgA = tid & 31;
  uint rrA[8][4];
  auto LOAD = [&](int tile, uint r[8][4]) {
    const int sb0 = (tile * 256) & (HW_ - 1);
#pragma unroll
    for (int e = 0; e < 8; ++e) {
      const int row = kcA * TG_ + e * T_ + t_;
      uint4 raw = *reinterpret_cast<const uint4*>(
          att_out + (size_t)row * HW_ + sb0 + cgA * 8);
      r[e][0] = raw.x; r[e][1] = raw.y; r[e][2] = raw.z; r[e][3] = raw.w;
    }
  };

  LOAD(tile0, rrA);

  bf16x8 wf[4][2];
#pragma unroll
  for (int mt = 0; mt < 4; ++mt)
#pragma unroll
    for (int c = 0; c < 2; ++c)
      wf[mt][c] = *reinterpret_cast<const bf16x8*>(
          Woutbf + (mt * 16 + lr) * 64 + c * 32 + lg * 8);

#pragma unroll
  for (int t = 0; t < K7B_TPB; ++t) {
    const int n0 = (tile0 + t) * 256;
    twrite(lds, K1_STRIDE, K1_NKC, rrA, kcA, cgA);
    __syncthreads();
    if (t + 1 < K7B_TPB) LOAD(tile0 + t + 1, rrA);

    for (int nt = 0; nt < 4; ++nt) {
      const int col = wv * 64 + nt * 16 + lr;
      bf16x8 xa[2];
#pragma unroll
      for (int c = 0; c < 2; ++c) {
        const int kc = c * 4 + lg;
        xa[c] = *reinterpret_cast<const bf16x8*>(
            lds + col * K1_STRIDE + ((kc + col) % K1_NKC) * 16);
      }
      f32x4 acc[4];
#pragma unroll
      for (int mt = 0; mt < 4; ++mt) acc[mt] = (f32x4){0.f, 0.f, 0.f, 0.f};
#pragma unroll
      for (int c = 0; c < 2; ++c)
#pragma unroll
        for (int mt = 0; mt < 4; ++mt)
          acc[mt] = __builtin_amdgcn_mfma_f32_16x16x32_bf16(xa[c], wf[mt][c], acc[mt], 0, 0, 0);
      const int nb = n0 + wv * 64 + nt * 16 + lg * 4;
#pragma unroll
      for (int mt = 0; mt < 4; ++mt) {
        const int o = mt * 16 + lr;
        *reinterpret_cast<float4*>(outb + (size_t)o * THW_ + nb) =
            (float4){acc[mt][0], acc[mt][1], acc[mt][2], acc[mt][3]};
      }
    }
    __syncthreads();
  }
}

extern "C" void kernel_launch(void* const* d_in, const int* in_sizes, int n_in,
                              void* d_out, int out_size, void* d_ws, size_t ws_size,
                              hipStream_t stream) {
  const float* x    = (const float*)d_in[0];
  const float* W1   = (const float*)d_in[1];
  const float* Wdw  = (const float*)d_in[2];
  const float* Wlin = (const float*)d_in[3];
  const float* blin = (const float*)d_in[4];
  const float* temp = (const float*)d_in[5];
  const float* Wout = (const float*)d_in[6];
  float* out = (float*)d_out;

  const size_t NY = (size_t)C3_ * THW_;          // 31,457,280 elems (60MB bf16)
  char* ws = (char*)d_ws;
  bf16* y1z = (bf16*)ws;                          // y1[b] = z[b] = y1z + b*NY
  bf16* y2  = (bf16*)(ws + 4 * NY);               // y2[b]
  char* E   = ws + 8 * NY;                        // extras base
  float* Gpart  = (float*)E;                      // 2 x 3,276,800 B (16 chunks)
  bf16* attnbf  = (bf16*)(E + 6553600);           // 2 x 245,760 B
  bf16* att_out = (bf16*)(E + 7045120);           // 2 x 20,971,520 B
  float* ssq    = (float*)(E + 48988160);         // 10,240 B
  bf16* W1bf    = (bf16*)(E + 48998400);          // 24,576 B
  bf16* Wlinbf  = (bf16*)(E + 49022976);          // 15,360 B
  bf16* Woutbf  = (bf16*)(E + 49038336);          // 8,192 B

  kprep<<<94, 256, 0, stream>>>(W1, Wlin, Wout, W1bf, Wlinbf, Woutbf, ssq);
  k1_mfma<<<dim3(THW_ / 128 / K1_TPB, 2, 2), 256, 0, stream>>>(x, W1bf, y1z);
  k2_dw<<<dim3(C3_ * T_ * 4, 2), 256, 0, stream>>>(y1z, Wdw, y2);
  k3_mfma<<<dim3(HW_ / 256 / K3_TPB, C2_, 2), 256, 0, stream>>>(y2, Wlinbf, blin, y1z, ssq);
  k5_mfma<<<dim3(16, NH_, 2), 256, 0, stream>>>(y1z, Gpart);
  k6_softmax<<<dim3(NH_ * TG_, 2), 128, 0, stream>>>(Gpart, ssq, temp, attnbf);
  k7a_mfma<<<dim3(HW_ / 256 / K7A_TPB, NH_, 2), 256, 0, stream>>>(y1z, attnbf, att_out);
  k7b_mfma<<<dim3(THW_ / 256 / K7B_TPB, 2), 256, 0, stream>>>(att_out, Woutbf, out);
}